// Round 1
// baseline (1162.485 us; speedup 1.0000x reference)
//
#include <hip/hip_runtime.h>

#define N_NODES 50000
#define N_EDGES 800000
#define D_FEAT 32
#define NUM_GRAPHS 64
#define FEATS 320

// ---------------- CSR construction ----------------

__global__ void hist_kernel(const int* __restrict__ dst, int* __restrict__ deg, int n) {
    int e = blockIdx.x * blockDim.x + threadIdx.x;
    if (e < n) atomicAdd(&deg[dst[e]], 1);
}

// inclusive scan of 1024-element chunks
__global__ void scan1_kernel(const int* __restrict__ deg, int* __restrict__ inc,
                             int* __restrict__ blksum, int n) {
    __shared__ int s[1024];
    int t = threadIdx.x;
    int i = blockIdx.x * 1024 + t;
    int v = (i < n) ? deg[i] : 0;
    s[t] = v;
    __syncthreads();
    for (int off = 1; off < 1024; off <<= 1) {
        int u = (t >= off) ? s[t - off] : 0;
        __syncthreads();
        s[t] += u;
        __syncthreads();
    }
    if (i < n) inc[i] = s[t];
    if (t == 1023) blksum[blockIdx.x] = s[1023];
}

// exclusive scan of block sums (nblk <= 64)
__global__ void scan2_kernel(const int* __restrict__ blksum, int* __restrict__ blkoff, int nblk) {
    __shared__ int s[64];
    int t = threadIdx.x;
    int v = (t < nblk) ? blksum[t] : 0;
    s[t] = v;
    __syncthreads();
    for (int off = 1; off < 64; off <<= 1) {
        int u = (t >= off) ? s[t - off] : 0;
        __syncthreads();
        s[t] += u;
        __syncthreads();
    }
    if (t < nblk) blkoff[t] = s[t] - v;   // exclusive
}

__global__ void scan3_kernel(const int* __restrict__ deg, const int* __restrict__ inc,
                             const int* __restrict__ blkoff, int* __restrict__ rowptr,
                             int* __restrict__ cursor, int n, int nedges) {
    int i = blockIdx.x * blockDim.x + threadIdx.x;
    if (i < n) {
        int ex = inc[i] - deg[i] + blkoff[i >> 10];
        rowptr[i] = ex;
        cursor[i] = ex;
    }
    if (i == 0) rowptr[n] = nedges;
}

__global__ void scatter_kernel(const int* __restrict__ src, const int* __restrict__ dst,
                               const float* __restrict__ w, int* __restrict__ cursor,
                               int* __restrict__ srcs, float* __restrict__ wsrt, int n) {
    int e = blockIdx.x * blockDim.x + threadIdx.x;
    if (e < n) {
        int d = dst[e];
        int pos = atomicAdd(&cursor[d], 1);
        srcs[pos] = src[e];
        wsrt[pos] = w[e];
    }
}

// ---------------- SpMM (pull, no atomics) ----------------
// 32 lanes per node; lane = feature (D=32) or float4 group (D=128)

__global__ void spmm32_kernel(const float* __restrict__ xin, int ldin,
                              float* __restrict__ yout, int ldout,
                              const int* __restrict__ rowptr, const int* __restrict__ srcs,
                              const float* __restrict__ wsrt, int n) {
    int lane = threadIdx.x & 31;
    int node = (blockIdx.x * blockDim.x + threadIdx.x) >> 5;
    if (node >= n) return;
    int e0 = rowptr[node], e1 = rowptr[node + 1];
    float acc = 0.f;
    for (int e = e0; e < e1; ++e) {
        int s = srcs[e];
        float w = wsrt[e];
        acc += xin[(size_t)s * ldin + lane] * w;
    }
    yout[(size_t)node * ldout + lane] = acc;
}

__global__ void spmm128_kernel(const float4* __restrict__ xin, float4* __restrict__ yout,
                               const int* __restrict__ rowptr, const int* __restrict__ srcs,
                               const float* __restrict__ wsrt, int n) {
    int lane = threadIdx.x & 31;   // covers 128 cols as float4
    int node = (blockIdx.x * blockDim.x + threadIdx.x) >> 5;
    if (node >= n) return;
    int e0 = rowptr[node], e1 = rowptr[node + 1];
    float4 acc = make_float4(0.f, 0.f, 0.f, 0.f);
    for (int e = e0; e < e1; ++e) {
        int s = srcs[e];
        float w = wsrt[e];
        float4 v = xin[(size_t)s * 32 + lane];
        acc.x += v.x * w; acc.y += v.y * w; acc.z += v.z * w; acc.w += v.w * w;
    }
    yout[(size_t)node * 32 + lane] = acc;
}

// ---------------- pooling (chunked, sorted-batch aware) ----------------

struct PoolTerm {
    const float* P;
    const float* Q;
    int ldP, ldQ, outcol, mode;   // mode 0: P, mode 1: |P - Q|
};
struct PoolArgs {
    PoolTerm t[4];
    int nterms;
};

__global__ void pool_kernel(PoolArgs a, const int* __restrict__ batch,
                            float* __restrict__ out, int chunk, int n) {
    int k = threadIdx.x >> 5;
    int f = threadIdx.x & 31;
    if (k >= a.nterms) return;
    int n0 = blockIdx.x * chunk;
    if (n0 >= n) return;
    int n1 = min(n0 + chunk, n);
    PoolTerm tm = a.t[k];
    float acc = 0.f;
    int gcur = batch[n0];
    for (int i = n0; i < n1; ++i) {
        int g = batch[i];
        if (g != gcur) {   // uniform across block (same i for all threads)
            atomicAdd(&out[gcur * FEATS + tm.outcol + f], acc);
            acc = 0.f;
            gcur = g;
        }
        float v;
        if (tm.mode == 0) v = tm.P[(size_t)i * tm.ldP + f];
        else v = fabsf(tm.P[(size_t)i * tm.ldP + f] - tm.Q[(size_t)i * tm.ldQ + f]);
        acc += v;
    }
    atomicAdd(&out[gcur * FEATS + tm.outcol + f], acc);
}

__global__ void counts_kernel(const int* __restrict__ batch, float* __restrict__ counts, int n) {
    __shared__ int h[NUM_GRAPHS];
    if (threadIdx.x < NUM_GRAPHS) h[threadIdx.x] = 0;
    __syncthreads();
    for (int i = blockIdx.x * blockDim.x + threadIdx.x; i < n; i += gridDim.x * blockDim.x)
        atomicAdd(&h[batch[i]], 1);
    __syncthreads();
    if (threadIdx.x < NUM_GRAPHS) {
        int v = h[threadIdx.x];
        if (v) atomicAdd(&counts[threadIdx.x], (float)v);
    }
}

__global__ void divide_kernel(float* __restrict__ out, const float* __restrict__ counts, int total) {
    int i = blockIdx.x * blockDim.x + threadIdx.x;
    if (i < total) out[i] /= fmaxf(counts[i / FEATS], 1.0f);
}

// ---------------- host launch ----------------

extern "C" void kernel_launch(void* const* d_in, const int* in_sizes, int n_in,
                              void* d_out, int out_size, void* d_ws, size_t ws_size,
                              hipStream_t stream) {
    const float* X     = (const float*)d_in[0];
    const int*   ei    = (const int*)d_in[1];
    const float* ew    = (const float*)d_in[2];
    const int*   batch = (const int*)d_in[3];
    float* out = (float*)d_out;

    const int N = N_NODES, E = N_EDGES;
    const int* src = ei;
    const int* dst = ei + E;

    char* base = (char*)d_ws;
    size_t off = 0;
    auto alloc = [&](size_t bytes) -> void* {
        void* p = base + off;
        off += (bytes + 255) & ~(size_t)255;
        return p;
    };
    float* U    = (float*)alloc((size_t)N * 128 * 4);  // first-diffusion collected scales, col blocks
    float* A    = (float*)alloc((size_t)N * 128 * 4);
    float* B    = (float*)alloc((size_t)N * 128 * 4);
    float* C    = (float*)alloc((size_t)N * 128 * 4);
    float* t32a = (float*)alloc((size_t)N * 32 * 4);
    float* t32b = (float*)alloc((size_t)N * 32 * 4);
    float* wsrt = (float*)alloc((size_t)E * 4);
    float* counts = (float*)alloc(64 * 4);
    int* deg    = (int*)alloc((size_t)N * 4);
    int* inc    = (int*)alloc((size_t)N * 4);
    int* rowptr = (int*)alloc((size_t)(N + 4) * 4);
    int* cursor = (int*)alloc((size_t)N * 4);
    int* blksum = (int*)alloc(64 * 4);
    int* blkoff = (int*)alloc(64 * 4);
    int* srcs   = (int*)alloc((size_t)E * 4);

    hipMemsetAsync(deg, 0, (size_t)N * 4, stream);
    hipMemsetAsync(out, 0, (size_t)out_size * 4, stream);
    hipMemsetAsync(counts, 0, 64 * 4, stream);

    // CSR by dst
    hist_kernel<<<(E + 255) / 256, 256, 0, stream>>>(dst, deg, E);
    const int NBLK = (N + 1023) / 1024; // 49
    scan1_kernel<<<NBLK, 1024, 0, stream>>>(deg, inc, blksum, N);
    scan2_kernel<<<1, 64, 0, stream>>>(blksum, blkoff, NBLK);
    scan3_kernel<<<(N + 255) / 256, 256, 0, stream>>>(deg, inc, blkoff, rowptr, cursor, N, E);
    scatter_kernel<<<(E + 255) / 256, 256, 0, stream>>>(src, dst, ew, cursor, srcs, wsrt, E);

    // ---- first diffusion, D=32; collected steps 1,2,4,8 -> U col-blocks 0..3
    const int SPMM_GRID = (N * 32) / 256;  // 6250
    auto spmm32L = [&](const float* in, int ldin, float* o, int ldout) {
        spmm32_kernel<<<SPMM_GRID, 256, 0, stream>>>(in, ldin, o, ldout, rowptr, srcs, wsrt, N);
    };
    spmm32L(X, 32, U + 0, 128);        // step1 -> d1
    spmm32L(U + 0, 128, U + 32, 128);  // step2 -> d2
    spmm32L(U + 32, 128, t32a, 32);    // step3
    spmm32L(t32a, 32, U + 64, 128);    // step4 -> d4
    spmm32L(U + 64, 128, t32a, 32);    // step5
    spmm32L(t32a, 32, t32b, 32);       // step6
    spmm32L(t32b, 32, t32a, 32);       // step7
    spmm32L(t32a, 32, U + 96, 128);    // step8 -> d8

    const int chunk = (N + 511) / 512; // 98 nodes per pooling block
    // F0 (cols 0..32) and F1 (cols 32..128) from U
    {
        PoolArgs p{};
        p.t[0] = {U + 96, nullptr, 128, 0,   0,  0};  // F0 = d8
        p.t[1] = {U + 0,  U + 32,  128, 128, 32, 1};  // |d1-d2|
        p.t[2] = {U + 32, U + 64,  128, 128, 64, 1};  // |d2-d4|
        p.t[3] = {U + 64, U + 96,  128, 128, 96, 1};  // |d4-d8|
        p.nterms = 4;
        pool_kernel<<<512, 128, 0, stream>>>(p, batch, out, chunk, N);
    }

    // ---- second diffusion, D=128 on U; F2 pooled right after each collected step
    auto spmm128L = [&](const float* in, float* o) {
        spmm128_kernel<<<SPMM_GRID, 256, 0, stream>>>((const float4*)in, (float4*)o,
                                                      rowptr, srcs, wsrt, N);
    };
    spmm128L(U, A);   // step1: Ud0 = A
    spmm128L(A, B);   // step2: Ud1 = B
    {   // jp=1: (j=0) -> F2 term 0 @ col 128
        PoolArgs p{};
        p.t[0] = {B + 0, A + 0, 128, 128, 128, 1};
        p.nterms = 1;
        pool_kernel<<<512, 128, 0, stream>>>(p, batch, out, chunk, N);
    }
    spmm128L(B, C);   // step3
    spmm128L(C, A);   // step4: Ud2 = A (prev Ud1 = B)
    {   // jp=2: (j=0)->term1 @160, (j=1)->term3 @224
        PoolArgs p{};
        p.t[0] = {A + 0,  B + 0,  128, 128, 160, 1};
        p.t[1] = {A + 32, B + 32, 128, 128, 224, 1};
        p.nterms = 2;
        pool_kernel<<<512, 128, 0, stream>>>(p, batch, out, chunk, N);
    }
    spmm128L(A, B);   // step5 (A = Ud2 preserved)
    spmm128L(B, C);   // step6
    spmm128L(C, B);   // step7
    spmm128L(B, C);   // step8: Ud3 = C (prev Ud2 = A)
    {   // jp=3: (j=0)->term2 @192, (j=1)->term4 @256, (j=2)->term5 @288
        PoolArgs p{};
        p.t[0] = {C + 0,  A + 0,  128, 128, 192, 1};
        p.t[1] = {C + 32, A + 32, 128, 128, 256, 1};
        p.t[2] = {C + 64, A + 64, 128, 128, 288, 1};
        p.nterms = 3;
        pool_kernel<<<512, 128, 0, stream>>>(p, batch, out, chunk, N);
    }

    counts_kernel<<<128, 256, 0, stream>>>(batch, counts, N);
    divide_kernel<<<(out_size + 255) / 256, 256, 0, stream>>>(out, counts, out_size);
}

// Round 2
// 462.597 us; speedup vs baseline: 2.5130x; 2.5130x over previous
//
#include <hip/hip_runtime.h>

#define N_NODES 50000
#define N_EDGES 800000
#define D_FEAT 32
#define NUM_GRAPHS 64
#define FEATS 320

// ---------------- CSR construction ----------------

__global__ void hist_kernel(const int* __restrict__ dst, int* __restrict__ deg, int n) {
    int e = blockIdx.x * blockDim.x + threadIdx.x;
    if (e < n) atomicAdd(&deg[dst[e]], 1);
}

// inclusive scan of 1024-element chunks
__global__ void scan1_kernel(const int* __restrict__ deg, int* __restrict__ inc,
                             int* __restrict__ blksum, int n) {
    __shared__ int s[1024];
    int t = threadIdx.x;
    int i = blockIdx.x * 1024 + t;
    int v = (i < n) ? deg[i] : 0;
    s[t] = v;
    __syncthreads();
    for (int off = 1; off < 1024; off <<= 1) {
        int u = (t >= off) ? s[t - off] : 0;
        __syncthreads();
        s[t] += u;
        __syncthreads();
    }
    if (i < n) inc[i] = s[t];
    if (t == 1023) blksum[blockIdx.x] = s[1023];
}

// exclusive scan of block sums (nblk <= 64)
__global__ void scan2_kernel(const int* __restrict__ blksum, int* __restrict__ blkoff, int nblk) {
    __shared__ int s[64];
    int t = threadIdx.x;
    int v = (t < nblk) ? blksum[t] : 0;
    s[t] = v;
    __syncthreads();
    for (int off = 1; off < 64; off <<= 1) {
        int u = (t >= off) ? s[t - off] : 0;
        __syncthreads();
        s[t] += u;
        __syncthreads();
    }
    if (t < nblk) blkoff[t] = s[t] - v;   // exclusive
}

__global__ void scan3_kernel(const int* __restrict__ deg, const int* __restrict__ inc,
                             const int* __restrict__ blkoff, int* __restrict__ rowptr,
                             int* __restrict__ cursor, int n, int nedges) {
    int i = blockIdx.x * blockDim.x + threadIdx.x;
    if (i < n) {
        int ex = inc[i] - deg[i] + blkoff[i >> 10];
        rowptr[i] = ex;
        cursor[i] = ex;
    }
    if (i == 0) rowptr[n] = nedges;
}

// packed 8B (src, w) single store per edge: halves scattered write-allocate traffic
__global__ void scatter_kernel(const int* __restrict__ src, const int* __restrict__ dst,
                               const float* __restrict__ w, int* __restrict__ cursor,
                               int2* __restrict__ edges, int n) {
    int e = blockIdx.x * blockDim.x + threadIdx.x;
    if (e < n) {
        int d = dst[e];
        int pos = atomicAdd(&cursor[d], 1);
        edges[pos] = make_int2(src[e], __float_as_int(w[e]));
    }
}

// ---------------- SpMM (pull, no atomics), D=32 ----------------
// 32 lanes per node; lane = feature. Packed edge record: one 8B load/edge.

__global__ void spmm32_kernel(const float* __restrict__ xin,
                              float* __restrict__ yout,
                              const int* __restrict__ rowptr,
                              const int2* __restrict__ edges, int n) {
    int lane = threadIdx.x & 31;
    int node = (blockIdx.x * blockDim.x + threadIdx.x) >> 5;
    if (node >= n) return;
    int e0 = rowptr[node], e1 = rowptr[node + 1];
    float acc = 0.f;
    int e = e0;
    // unroll x4: batch up edge-record loads + independent gathers for MLP
    for (; e + 4 <= e1; e += 4) {
        int2 p0 = edges[e + 0];
        int2 p1 = edges[e + 1];
        int2 p2 = edges[e + 2];
        int2 p3 = edges[e + 3];
        float v0 = xin[(size_t)p0.x * 32 + lane];
        float v1 = xin[(size_t)p1.x * 32 + lane];
        float v2 = xin[(size_t)p2.x * 32 + lane];
        float v3 = xin[(size_t)p3.x * 32 + lane];
        acc += v0 * __int_as_float(p0.y);
        acc += v1 * __int_as_float(p1.y);
        acc += v2 * __int_as_float(p2.y);
        acc += v3 * __int_as_float(p3.y);
    }
    for (; e < e1; ++e) {
        int2 p = edges[e];
        acc += xin[(size_t)p.x * 32 + lane] * __int_as_float(p.y);
    }
    yout[(size_t)node * 32 + lane] = acc;
}

// ---------------- fused pooling: all 10 feature terms in one launch ----------------
// term k covers out cols [32k, 32k+32); Q==nullptr -> raw P, else |P - Q|

struct PoolArgs10 {
    const float* P[10];
    const float* Q[10];
};

__global__ __launch_bounds__(320) void pool_kernel(PoolArgs10 a, const int* __restrict__ batch,
                                                   float* __restrict__ out, int chunk, int n) {
    int k = threadIdx.x >> 5;
    int f = threadIdx.x & 31;
    int n0 = blockIdx.x * chunk;
    if (n0 >= n) return;
    int n1 = min(n0 + chunk, n);
    const float* __restrict__ P = a.P[k];
    const float* __restrict__ Q = a.Q[k];
    float acc = 0.f;
    int gcur = batch[n0];
    for (int i = n0; i < n1; ++i) {
        int g = batch[i];
        if (g != gcur) {   // uniform across block
            atomicAdd(&out[gcur * FEATS + k * 32 + f], acc);
            acc = 0.f;
            gcur = g;
        }
        float v = P[(size_t)i * 32 + f];
        if (Q) v = fabsf(v - Q[(size_t)i * 32 + f]);
        acc += v;
    }
    atomicAdd(&out[gcur * FEATS + k * 32 + f], acc);
}

__global__ void counts_kernel(const int* __restrict__ batch, float* __restrict__ counts, int n) {
    __shared__ int h[NUM_GRAPHS];
    if (threadIdx.x < NUM_GRAPHS) h[threadIdx.x] = 0;
    __syncthreads();
    for (int i = blockIdx.x * blockDim.x + threadIdx.x; i < n; i += gridDim.x * blockDim.x)
        atomicAdd(&h[batch[i]], 1);
    __syncthreads();
    if (threadIdx.x < NUM_GRAPHS) {
        int v = h[threadIdx.x];
        if (v) atomicAdd(&counts[threadIdx.x], (float)v);
    }
}

__global__ void divide_kernel(float* __restrict__ out, const float* __restrict__ counts, int total) {
    int i = blockIdx.x * blockDim.x + threadIdx.x;
    if (i < total) out[i] /= fmaxf(counts[i / FEATS], 1.0f);
}

// ---------------- host launch ----------------

extern "C" void kernel_launch(void* const* d_in, const int* in_sizes, int n_in,
                              void* d_out, int out_size, void* d_ws, size_t ws_size,
                              hipStream_t stream) {
    const float* X     = (const float*)d_in[0];
    const int*   ei    = (const int*)d_in[1];
    const float* ew    = (const float*)d_in[2];
    const int*   batch = (const int*)d_in[3];
    float* out = (float*)d_out;

    const int N = N_NODES, E = N_EDGES;
    const int* src = ei;
    const int* dst = ei + E;

    char* base = (char*)d_ws;
    size_t off = 0;
    auto alloc = [&](size_t bytes) -> void* {
        void* p = base + off;
        off += (bytes + 255) & ~(size_t)255;
        return p;
    };
    // diffusion chain buffers y[k] = P^k X, k=1..12 (y[0] aliases X)
    float* y[13];
    y[0] = (float*)X;
    for (int k = 1; k <= 12; ++k) y[k] = (float*)alloc((size_t)N * 32 * 4);

    float* counts = (float*)alloc(64 * 4);
    int*  deg    = (int*)alloc((size_t)N * 4);
    int*  inc    = (int*)alloc((size_t)N * 4);
    int*  rowptr = (int*)alloc((size_t)(N + 4) * 4);
    int*  cursor = (int*)alloc((size_t)N * 4);
    int*  blksum = (int*)alloc(64 * 4);
    int*  blkoff = (int*)alloc(64 * 4);
    int2* edges  = (int2*)alloc((size_t)E * 8);

    hipMemsetAsync(deg, 0, (size_t)N * 4, stream);
    hipMemsetAsync(out, 0, (size_t)out_size * 4, stream);
    hipMemsetAsync(counts, 0, 64 * 4, stream);

    // CSR by dst
    hist_kernel<<<(E + 255) / 256, 256, 0, stream>>>(dst, deg, E);
    const int NBLK = (N + 1023) / 1024; // 49
    scan1_kernel<<<NBLK, 1024, 0, stream>>>(deg, inc, blksum, N);
    scan2_kernel<<<1, 64, 0, stream>>>(blksum, blkoff, NBLK);
    scan3_kernel<<<(N + 255) / 256, 256, 0, stream>>>(deg, inc, blkoff, rowptr, cursor, N, E);
    scatter_kernel<<<(E + 255) / 256, 256, 0, stream>>>(src, dst, ew, cursor, edges, E);

    // ---- single D=32 diffusion chain: y[k] = P y[k-1], k = 1..12
    // (second diffusion of the reference is algebraically P^(2^jp + 2^j) X,
    //  elementwise the exact same FP op sequence as chaining propagates)
    const int SPMM_GRID = (N * 32) / 256;  // 6250
    for (int k = 1; k <= 12; ++k) {
        spmm32_kernel<<<SPMM_GRID, 256, 0, stream>>>(y[k - 1], y[k], rowptr, edges, N);
    }

    // ---- fused pooling of all 10 feature column-blocks
    // F0 = y8 | F1: |y1-y2|, |y2-y4|, |y4-y8|
    // F2 (ref order): |y3-y2|, |y5-y3|, |y9-y5|, |y6-y4|, |y10-y6|, |y12-y8|
    {
        PoolArgs10 p{};
        const float* Ps[10] = {y[8], y[1], y[2], y[4], y[3], y[5], y[9], y[6], y[10], y[12]};
        const float* Qs[10] = {nullptr, y[2], y[4], y[8], y[2], y[3], y[5], y[4], y[6], y[8]};
        for (int k = 0; k < 10; ++k) { p.P[k] = Ps[k]; p.Q[k] = Qs[k]; }
        const int chunk = (N + 511) / 512; // 98 nodes per block
        pool_kernel<<<512, 320, 0, stream>>>(p, batch, out, chunk, N);
    }

    counts_kernel<<<128, 256, 0, stream>>>(batch, counts, N);
    divide_kernel<<<(out_size + 255) / 256, 256, 0, stream>>>(out, counts, out_size);
}

// Round 3
// 374.394 us; speedup vs baseline: 3.1050x; 1.2356x over previous
//
#include <hip/hip_runtime.h>

#define N_NODES 50000
#define N_EDGES 800000
#define D_FEAT 32
#define NUM_GRAPHS 64
#define FEATS 320

// bf16 helpers (RNE pack, shift unpack) — values are finite, no NaN path needed
__device__ __forceinline__ unsigned short f2bf(float f) {
    unsigned int u = __float_as_uint(f);
    u = (u + 0x7fffu + ((u >> 16) & 1u)) >> 16;
    return (unsigned short)u;
}
__device__ __forceinline__ float bf2f(unsigned short h) {
    return __uint_as_float((unsigned int)h << 16);
}

// ---------------- CSR construction ----------------

__global__ void hist_kernel(const int* __restrict__ dst, int* __restrict__ deg, int n) {
    int e = blockIdx.x * blockDim.x + threadIdx.x;
    if (e < n) atomicAdd(&deg[dst[e]], 1);
}

__global__ void scan1_kernel(const int* __restrict__ deg, int* __restrict__ inc,
                             int* __restrict__ blksum, int n) {
    __shared__ int s[1024];
    int t = threadIdx.x;
    int i = blockIdx.x * 1024 + t;
    int v = (i < n) ? deg[i] : 0;
    s[t] = v;
    __syncthreads();
    for (int off = 1; off < 1024; off <<= 1) {
        int u = (t >= off) ? s[t - off] : 0;
        __syncthreads();
        s[t] += u;
        __syncthreads();
    }
    if (i < n) inc[i] = s[t];
    if (t == 1023) blksum[blockIdx.x] = s[1023];
}

__global__ void scan2_kernel(const int* __restrict__ blksum, int* __restrict__ blkoff, int nblk) {
    __shared__ int s[64];
    int t = threadIdx.x;
    int v = (t < nblk) ? blksum[t] : 0;
    s[t] = v;
    __syncthreads();
    for (int off = 1; off < 64; off <<= 1) {
        int u = (t >= off) ? s[t - off] : 0;
        __syncthreads();
        s[t] += u;
        __syncthreads();
    }
    if (t < nblk) blkoff[t] = s[t] - v;   // exclusive
}

__global__ void scan3_kernel(const int* __restrict__ deg, const int* __restrict__ inc,
                             const int* __restrict__ blkoff, int* __restrict__ rowptr,
                             int* __restrict__ cursor, int n, int nedges) {
    int i = blockIdx.x * blockDim.x + threadIdx.x;
    if (i < n) {
        int ex = inc[i] - deg[i] + blkoff[i >> 10];
        rowptr[i] = ex;
        cursor[i] = ex;
    }
    if (i == 0) rowptr[n] = nedges;
}

__global__ void scatter_kernel(const int* __restrict__ src, const int* __restrict__ dst,
                               const float* __restrict__ w, int* __restrict__ cursor,
                               int2* __restrict__ edges, int n) {
    int e = blockIdx.x * blockDim.x + threadIdx.x;
    if (e < n) {
        int d = dst[e];
        int pos = atomicAdd(&cursor[d], 1);
        edges[pos] = make_int2(src[e], __float_as_int(w[e]));
    }
}

// ---------------- X -> bf16 conversion ----------------

__global__ void cvt_kernel(const float4* __restrict__ xin, ushort4* __restrict__ xout, int n4) {
    int i = blockIdx.x * blockDim.x + threadIdx.x;
    if (i < n4) {
        float4 v = xin[i];
        ushort4 o;
        o.x = f2bf(v.x); o.y = f2bf(v.y); o.z = f2bf(v.z); o.w = f2bf(v.w);
        xout[i] = o;
    }
}

// ---------------- SpMM (pull, no atomics), D=32 bf16 ----------------
// 16 lanes per node; lane owns cols 2l,2l+1 as ushort2. Row = 64B gather.
// fp32 accumulate, bf16 RNE store.

__global__ void spmm_kernel(const ushort2* __restrict__ xin,
                            ushort2* __restrict__ yout,
                            const int* __restrict__ rowptr,
                            const int2* __restrict__ edges, int n) {
    int lane = threadIdx.x & 15;
    int node = (blockIdx.x * blockDim.x + threadIdx.x) >> 4;
    if (node >= n) return;
    int e0 = rowptr[node], e1 = rowptr[node + 1];
    float ax = 0.f, ay = 0.f;
    int e = e0;
    for (; e + 4 <= e1; e += 4) {
        int2 p0 = edges[e + 0];
        int2 p1 = edges[e + 1];
        int2 p2 = edges[e + 2];
        int2 p3 = edges[e + 3];
        ushort2 v0 = xin[(size_t)p0.x * 16 + lane];
        ushort2 v1 = xin[(size_t)p1.x * 16 + lane];
        ushort2 v2 = xin[(size_t)p2.x * 16 + lane];
        ushort2 v3 = xin[(size_t)p3.x * 16 + lane];
        float w0 = __int_as_float(p0.y), w1 = __int_as_float(p1.y);
        float w2 = __int_as_float(p2.y), w3 = __int_as_float(p3.y);
        ax += bf2f(v0.x) * w0; ay += bf2f(v0.y) * w0;
        ax += bf2f(v1.x) * w1; ay += bf2f(v1.y) * w1;
        ax += bf2f(v2.x) * w2; ay += bf2f(v2.y) * w2;
        ax += bf2f(v3.x) * w3; ay += bf2f(v3.y) * w3;
    }
    for (; e < e1; ++e) {
        int2 p = edges[e];
        ushort2 v = xin[(size_t)p.x * 16 + lane];
        float w = __int_as_float(p.y);
        ax += bf2f(v.x) * w; ay += bf2f(v.y) * w;
    }
    yout[(size_t)node * 16 + lane] = make_ushort2(f2bf(ax), f2bf(ay));
}

// ---------------- fused pooling: all 10 feature terms in one launch ----------------
// term k covers out cols [32k, 32k+32); Q==nullptr -> raw P, else |P - Q|

struct PoolArgs10 {
    const unsigned short* P[10];
    const unsigned short* Q[10];
};

__global__ __launch_bounds__(320) void pool_kernel(PoolArgs10 a, const int* __restrict__ batch,
                                                   float* __restrict__ out, int chunk, int n) {
    int k = threadIdx.x >> 5;
    int f = threadIdx.x & 31;
    int n0 = blockIdx.x * chunk;
    if (n0 >= n) return;
    int n1 = min(n0 + chunk, n);
    const unsigned short* __restrict__ P = a.P[k];
    const unsigned short* __restrict__ Q = a.Q[k];
    float acc = 0.f;
    int gcur = batch[n0];
    for (int i = n0; i < n1; ++i) {
        int g = batch[i];
        if (g != gcur) {   // uniform across block
            atomicAdd(&out[gcur * FEATS + k * 32 + f], acc);
            acc = 0.f;
            gcur = g;
        }
        float v = bf2f(P[(size_t)i * 32 + f]);
        if (Q) v = fabsf(v - bf2f(Q[(size_t)i * 32 + f]));
        acc += v;
    }
    atomicAdd(&out[gcur * FEATS + k * 32 + f], acc);
}

__global__ void counts_kernel(const int* __restrict__ batch, float* __restrict__ counts, int n) {
    __shared__ int h[NUM_GRAPHS];
    if (threadIdx.x < NUM_GRAPHS) h[threadIdx.x] = 0;
    __syncthreads();
    for (int i = blockIdx.x * blockDim.x + threadIdx.x; i < n; i += gridDim.x * blockDim.x)
        atomicAdd(&h[batch[i]], 1);
    __syncthreads();
    if (threadIdx.x < NUM_GRAPHS) {
        int v = h[threadIdx.x];
        if (v) atomicAdd(&counts[threadIdx.x], (float)v);
    }
}

__global__ void divide_kernel(float* __restrict__ out, const float* __restrict__ counts, int total) {
    int i = blockIdx.x * blockDim.x + threadIdx.x;
    if (i < total) out[i] /= fmaxf(counts[i / FEATS], 1.0f);
}

// ---------------- host launch ----------------

extern "C" void kernel_launch(void* const* d_in, const int* in_sizes, int n_in,
                              void* d_out, int out_size, void* d_ws, size_t ws_size,
                              hipStream_t stream) {
    const float* X     = (const float*)d_in[0];
    const int*   ei    = (const int*)d_in[1];
    const float* ew    = (const float*)d_in[2];
    const int*   batch = (const int*)d_in[3];
    float* out = (float*)d_out;

    const int N = N_NODES, E = N_EDGES;
    const int* src = ei;
    const int* dst = ei + E;

    char* base = (char*)d_ws;
    size_t off = 0;
    auto alloc = [&](size_t bytes) -> void* {
        void* p = base + off;
        off += (bytes + 255) & ~(size_t)255;
        return p;
    };
    // bf16 diffusion chain buffers y[k] = P^k X, k=0..12 (y[0] = bf16(X))
    unsigned short* y[13];
    for (int k = 0; k <= 12; ++k) y[k] = (unsigned short*)alloc((size_t)N * 32 * 2);

    float* counts = (float*)alloc(64 * 4);
    int*  deg    = (int*)alloc((size_t)N * 4);
    int*  inc    = (int*)alloc((size_t)N * 4);
    int*  rowptr = (int*)alloc((size_t)(N + 4) * 4);
    int*  cursor = (int*)alloc((size_t)N * 4);
    int*  blksum = (int*)alloc(64 * 4);
    int*  blkoff = (int*)alloc(64 * 4);
    int2* edges  = (int2*)alloc((size_t)E * 8);

    hipMemsetAsync(deg, 0, (size_t)N * 4, stream);
    hipMemsetAsync(out, 0, (size_t)out_size * 4, stream);
    hipMemsetAsync(counts, 0, 64 * 4, stream);

    // CSR by dst
    hist_kernel<<<(E + 255) / 256, 256, 0, stream>>>(dst, deg, E);
    const int NBLK = (N + 1023) / 1024; // 49
    scan1_kernel<<<NBLK, 1024, 0, stream>>>(deg, inc, blksum, N);
    scan2_kernel<<<1, 64, 0, stream>>>(blksum, blkoff, NBLK);
    scan3_kernel<<<(N + 255) / 256, 256, 0, stream>>>(deg, inc, blkoff, rowptr, cursor, N, E);
    scatter_kernel<<<(E + 255) / 256, 256, 0, stream>>>(src, dst, ew, cursor, edges, E);

    // X -> bf16
    cvt_kernel<<<(N * 32 / 4 + 255) / 256, 256, 0, stream>>>((const float4*)X, (ushort4*)y[0],
                                                             N * 32 / 4);

    // ---- single D=32 bf16 diffusion chain: y[k] = P y[k-1], k = 1..12
    const int SPMM_GRID = (N * 16) / 256;  // 3125 blocks, 16 nodes/block
    for (int k = 1; k <= 12; ++k) {
        spmm_kernel<<<SPMM_GRID, 256, 0, stream>>>((const ushort2*)y[k - 1], (ushort2*)y[k],
                                                   rowptr, edges, N);
    }

    // ---- fused pooling of all 10 feature column-blocks
    // F0 = y8 | F1: |y1-y2|, |y2-y4|, |y4-y8|
    // F2 (ref order): |y3-y2|, |y5-y3|, |y9-y5|, |y6-y4|, |y10-y6|, |y12-y8|
    {
        PoolArgs10 p{};
        const unsigned short* Ps[10] = {y[8], y[1], y[2], y[4], y[3], y[5], y[9], y[6], y[10], y[12]};
        const unsigned short* Qs[10] = {nullptr, y[2], y[4], y[8], y[2], y[3], y[5], y[4], y[6], y[8]};
        for (int k = 0; k < 10; ++k) { p.P[k] = Ps[k]; p.Q[k] = Qs[k]; }
        const int chunk = (N + 511) / 512; // 98 nodes per block
        pool_kernel<<<512, 320, 0, stream>>>(p, batch, out, chunk, N);
    }

    counts_kernel<<<128, 256, 0, stream>>>(batch, counts, N);
    divide_kernel<<<(out_size + 255) / 256, 256, 0, stream>>>(out, counts, out_size);
}